// Round 1
// 278.472 us; speedup vs baseline: 1.0173x; 1.0173x over previous
//
#include <hip/hip_runtime.h>

// Problem constants (B,S,D_IN,D_HID,D_OUT) = (8,4096,512,1024,512)
#define B_    8
#define S_    4096
#define DIN   512
#define DHID  1024
#define DOUT  512
#define M_    (B_*S_)          // 32768
#define NCAT  (DHID + DOUT)    // 1536
#define CH2   32
#define NCH2  (S_/CH2)         // 128

typedef __bf16 bf16x8 __attribute__((ext_vector_type(8)));
typedef float  floatx4 __attribute__((ext_vector_type(4)));

__device__ __forceinline__ unsigned short f2bf(float f) {
  unsigned u = __builtin_bit_cast(unsigned, f);
  u = (u + 0x7FFFu + ((u >> 16) & 1u)) >> 16;   // RNE
  return (unsigned short)u;
}
__device__ __forceinline__ float bf2f(unsigned short h) {
  unsigned u = ((unsigned)h) << 16;
  return __builtin_bit_cast(float, u);
}

__device__ __forceinline__ void gl_lds16(const unsigned short* g, unsigned short* l) {
  __builtin_amdgcn_global_load_lds((const __attribute__((address_space(1))) void*)g,
                                   (__attribute__((address_space(3))) void*)l, 16, 0, 0);
}

// ---------- fused prep: wcat | woutt | a_s | x->bf16 (single launch) ----------
__global__ void prep_all(const float* __restrict__ logit,
                         const float* __restrict__ Win, const float* __restrict__ Wdx,
                         const float* __restrict__ Wout, const float* __restrict__ x,
                         float* __restrict__ a_s,
                         unsigned short* __restrict__ wcat,
                         unsigned short* __restrict__ woutt,
                         unsigned short* __restrict__ xb) {
  int bx = blockIdx.x;
  if (bx < 3072) {                       // Wcat^T: n in [0,1536), k in [0,512)
    int idx = bx * 256 + threadIdx.x;
    int n = idx >> 9, k = idx & 511;
    float v = (n < DHID) ? Win[(size_t)k * DHID + n] : Wdx[(size_t)k * DOUT + (n - DHID)];
    wcat[idx] = f2bf(v);
  } else if (bx < 5120) {                // Wout^T: n in [0,512), k in [0,1024)
    int idx = (bx - 3072) * 256 + threadIdx.x;
    int n = idx >> 10, k = idx & 1023;
    woutt[idx] = f2bf(Wout[(size_t)k * DOUT + n]);
  } else if (bx < 5124) {                // a_s
    int d = (bx - 5120) * 256 + threadIdx.x;
    if (d < DHID) {
      float a = 1.f / (1.f + expf(-logit[d]));
      a_s[d] = a;
      a_s[DHID + d] = sqrtf(fmaxf(1.f - a * a, 0.f));
    }
  } else {                               // x fp32 -> bf16, 8 elems/thread
    size_t i = (size_t)(bx - 5124) * 256 + threadIdx.x;
    const float4* p = (const float4*)x;
    float4 v0 = p[i * 2];
    float4 v1 = p[i * 2 + 1];
    uint4 o;
    o.x = (unsigned)f2bf(v0.x) | ((unsigned)f2bf(v0.y) << 16);
    o.y = (unsigned)f2bf(v0.z) | ((unsigned)f2bf(v0.w) << 16);
    o.z = (unsigned)f2bf(v1.x) | ((unsigned)f2bf(v1.y) << 16);
    o.w = (unsigned)f2bf(v1.z) | ((unsigned)f2bf(v1.w) << 16);
    *(uint4*)&xb[i * 8] = o;
  }
}

// ---------- GEMM1: 256x256 tile, BK=32, 4-slot circular pipeline, counted vmcnt ----------
// C = A(MxK=512) * Wcat^T. n<1024: u=(c+b_in)*s bf16 + fused chunk-local scan -> carry;
// n>=1024: dx=c+b_dx bf16.
// 8 waves (2M x 4N), each owns 128x64. LDS: 4 slots x (A 16KB + B 16KB) = 128 KB.
// Swizzle: LDS linear (global_load_lds), source pre-swizzled, ds_read applies same
// involution: 16B-chunk c' = c ^ ((row>>1)&3)  -> 2-way (free) bank access.
__global__ __launch_bounds__(512, 2) void gemm1(
    const unsigned short* __restrict__ A,
    const unsigned short* __restrict__ Bt,
    const float* __restrict__ a_s,
    const float* __restrict__ bin,
    const float* __restrict__ bdx,
    unsigned short* __restrict__ u_out,
    unsigned short* __restrict__ dx_buf,
    float* __restrict__ carry)
{
  __shared__ __align__(16) unsigned char smem[131072];

  const int tid  = threadIdx.x;
  const int lane = tid & 63, wid = tid >> 6;
  const int r16  = lane & 15, quad = lane >> 4;
  const int wm = (wid >> 2) * 128, wn = (wid & 3) * 64;
  const int csw = (quad ^ ((r16 >> 1) & 3)) << 4;    // swizzled 16B-chunk byte offset

  // XCD-aware swizzle: 768 blocks = 8 XCD * 96; within XCD: 16 m-tiles x 6 n-tiles
  const int flat = blockIdx.x;
  const int jj = (flat & 7) * 96 + (flat >> 3);
  const int nt = jj % 6, mt = jj / 6;
  const int n0 = nt * 256, m0 = mt * 256;

  // per-lane pre-swizzled global staging sources (2 A-loads + 2 B-loads / K-tile)
  const unsigned oA0 = (unsigned)wid * 1024u + (unsigned)lane * 16u;  // linear LDS byte
  const unsigned oA1 = oA0 + 8192u;
  const int rA0 = oA0 >> 6, cA0 = (int)((oA0 >> 4) & 3u) ^ ((rA0 >> 1) & 3);
  const int rA1 = oA1 >> 6, cA1 = (int)((oA1 >> 4) & 3u) ^ ((rA1 >> 1) & 3);
  const unsigned short* sA0 = A  + (size_t)(m0 + rA0) * DIN + cA0 * 8;
  const unsigned short* sA1 = A  + (size_t)(m0 + rA1) * DIN + cA1 * 8;
  const unsigned short* sB0 = Bt + (size_t)(n0 + rA0) * DIN + cA0 * 8;
  const unsigned short* sB1 = Bt + (size_t)(n0 + rA1) * DIN + cA1 * 8;

  unsigned char* lds = smem;
  const unsigned dA0 = (unsigned)wid * 1024u, dA1 = dA0 + 8192u;

  floatx4 acc[8][4] = {};

  auto stage = [&](int slot, int kt) {
    unsigned char* d = lds + slot * 32768;
    const int ko = kt * 32;
    gl_lds16(sA0 + ko, (unsigned short*)(d + dA0));
    gl_lds16(sA1 + ko, (unsigned short*)(d + dA1));
    gl_lds16(sB0 + ko, (unsigned short*)(d + 16384 + dA0));
    gl_lds16(sB1 + ko, (unsigned short*)(d + 16384 + dA1));
  };

  auto compute = [&](int slot) {
    const unsigned char* pA = lds + slot * 32768;
    const unsigned char* pB = pA + 16384;
    bf16x8 af[8], bfr[4];
#pragma unroll
    for (int j = 0; j < 4; ++j)
      bfr[j] = *(const bf16x8*)(pB + (wn + j * 16 + r16) * 64 + csw);
#pragma unroll
    for (int i = 0; i < 8; ++i)
      af[i] = *(const bf16x8*)(pA + (wm + i * 16 + r16) * 64 + csw);
    __builtin_amdgcn_s_setprio(1);
#pragma unroll
    for (int i = 0; i < 8; ++i)
#pragma unroll
      for (int j = 0; j < 4; ++j)
        acc[i][j] = __builtin_amdgcn_mfma_f32_16x16x32_bf16(af[i], bfr[j], acc[i][j], 0, 0, 0);
    __builtin_amdgcn_s_setprio(0);
  };

  // prologue: 3 tiles in flight
  stage(0, 0); stage(1, 1); stage(2, 2);
  asm volatile("s_waitcnt vmcnt(8)" ::: "memory");     // tile 0 landed
  __builtin_amdgcn_s_barrier();

  // main loop: stage t+3 | compute t | wait tile t+1 (2 tiles stay in flight)
  for (int t = 0; t < 13; ++t) {
    stage((t + 3) & 3, t + 3);
    compute(t & 3);
    asm volatile("s_waitcnt vmcnt(8) lgkmcnt(0)" ::: "memory");
    __builtin_amdgcn_s_barrier();
  }
  compute(1);
  asm volatile("s_waitcnt vmcnt(4) lgkmcnt(0)" ::: "memory");
  __builtin_amdgcn_s_barrier();
  compute(2);
  asm volatile("s_waitcnt vmcnt(0) lgkmcnt(0)" ::: "memory");
  __builtin_amdgcn_s_barrier();
  compute(3);
  asm volatile("s_waitcnt lgkmcnt(0)" ::: "memory");
  __builtin_amdgcn_s_barrier();

  // ---- epilogue: 4 passes of 64 rows through LDS (fp32, stride 260) ----
  float* stg = (float*)smem;
  const bool isU = (n0 < DHID);

  // store mapping: thread -> (8-col group, base row)
  const int sg = tid & 31, rw0 = tid >> 5;
  // scan mapping: thread -> (col, 32-row chunk)  [512 = 256 cols x 2 chunks]
  const int colS = tid & 255, ch = tid >> 8;

  float aa = 0.f, sbi = 0.f, ssc = 0.f;
  float4 bv0, bv1, sv0, sv1;
  if (isU) {
    aa  = a_s[n0 + colS];
    sbi = bin[n0 + colS];
    ssc = a_s[DHID + n0 + colS];
    bv0 = *(const float4*)&bin[n0 + sg * 8];
    bv1 = *(const float4*)&bin[n0 + sg * 8 + 4];
    sv0 = *(const float4*)&a_s[DHID + n0 + sg * 8];
    sv1 = *(const float4*)&a_s[DHID + n0 + sg * 8 + 4];
  } else {
    bv0 = *(const float4*)&bdx[n0 - DHID + sg * 8];
    bv1 = *(const float4*)&bdx[n0 - DHID + sg * 8 + 4];
    sv0 = bv0; sv1 = bv1;  // unused
  }

#pragma unroll
  for (int p = 0; p < 4; ++p) {
    if ((wid >> 2) == (p >> 1)) {
      const int ib = (p & 1) * 4;
#pragma unroll
      for (int ii = 0; ii < 4; ++ii) {
#pragma unroll
        for (int j = 0; j < 4; ++j) {
          const int col = (wid & 3) * 64 + j * 16 + r16;
#pragma unroll
          for (int r = 0; r < 4; ++r)
            stg[(ii * 16 + quad * 4 + r) * 260 + col] = acc[ib + ii][j][r];
        }
      }
    }
    asm volatile("s_waitcnt lgkmcnt(0)" ::: "memory");
    __builtin_amdgcn_s_barrier();

    const int gmb = m0 + p * 64;
    if (isU) {
      // fused scan1: chunk-local weighted sum over 32 rows (one task per thread)
      float P = 0.f;
      const float* sp = &stg[(ch * 32) * 260 + colS];
#pragma unroll
      for (int r = 0; r < 32; ++r) { P = fmaf(aa, P, (sp[0] + sbi) * ssc); sp += 260; }
      const int gm0 = gmb + ch * 32;
      carry[((size_t)(gm0 >> 12) * NCH2 + ((gm0 & 4095) >> 5)) * DHID + n0 + colS] = P;
      // u stores: u = (c + b_in) * s  (bf16)
#pragma unroll
      for (int q = 0; q < 4; ++q) {
        const int lr = rw0 + q * 16;
        float4 v0 = *(const float4*)&stg[lr * 260 + sg * 8];
        float4 v1 = *(const float4*)&stg[lr * 260 + sg * 8 + 4];
        union { unsigned short s[8]; uint4 u4; } ub;
        ub.s[0] = f2bf((v0.x + bv0.x) * sv0.x);
        ub.s[1] = f2bf((v0.y + bv0.y) * sv0.y);
        ub.s[2] = f2bf((v0.z + bv0.z) * sv0.z);
        ub.s[3] = f2bf((v0.w + bv0.w) * sv0.w);
        ub.s[4] = f2bf((v1.x + bv1.x) * sv1.x);
        ub.s[5] = f2bf((v1.y + bv1.y) * sv1.y);
        ub.s[6] = f2bf((v1.z + bv1.z) * sv1.z);
        ub.s[7] = f2bf((v1.w + bv1.w) * sv1.w);
        *(uint4*)&u_out[(size_t)(gmb + lr) * DHID + n0 + sg * 8] = ub.u4;
      }
    } else {
      // dx stores: dx = c + b_dx  (bf16)
#pragma unroll
      for (int q = 0; q < 4; ++q) {
        const int lr = rw0 + q * 16;
        float4 v0 = *(const float4*)&stg[lr * 260 + sg * 8];
        float4 v1 = *(const float4*)&stg[lr * 260 + sg * 8 + 4];
        union { unsigned short s[8]; uint4 u4; } ub;
        ub.s[0] = f2bf(v0.x + bv0.x);
        ub.s[1] = f2bf(v0.y + bv0.y);
        ub.s[2] = f2bf(v0.z + bv0.z);
        ub.s[3] = f2bf(v0.w + bv0.w);
        ub.s[4] = f2bf(v1.x + bv1.x);
        ub.s[5] = f2bf(v1.y + bv1.y);
        ub.s[6] = f2bf(v1.z + bv1.z);
        ub.s[7] = f2bf(v1.w + bv1.w);
        *(uint4*)&dx_buf[(size_t)(gmb + lr) * DOUT + (n0 - DHID) + sg * 8] = ub.u4;
      }
    }
    asm volatile("s_waitcnt lgkmcnt(0)" ::: "memory");
    __builtin_amdgcn_s_barrier();
  }
}

// ---------- GEMM2 (proven round-4 core, 128x128 tile, MODE 1 only) ----------
template <int K, int MODE, int NB>
__global__ __launch_bounds__(256, 4) void gemm_bt(
    const unsigned short* __restrict__ A,
    const unsigned short* __restrict__ Bt,
    const float* __restrict__ a_s,
    const float* __restrict__ bias0,
    const float* __restrict__ bias1,
    unsigned short* __restrict__ u_out,
    unsigned short* __restrict__ dx_buf,
    float* __restrict__ out,
    float* __restrict__ carry)
{
  __shared__ __align__(16) unsigned char smem[32768];
  unsigned short* lA = (unsigned short*)smem;            // 128 x 64 bf16
  unsigned short* lB = (unsigned short*)(smem + 16384);  // 128 x 64 bf16
  float* stg  = (float*)smem;                            // epilogue stage, 32 x 132 fp32
  float* ltmp = (float*)(smem + 16896);                  // 128 floats (scan combine)

  const int tid = threadIdx.x;
  const int flat = blockIdx.y * gridDim.x + blockIdx.x;
  const int xcd = flat & 7;
  const int j = flat >> 3;
  const int n0 = (j % NB) * 128;
  const int m0 = ((j / NB) * 8 + xcd) * 128;

  const int wid = tid >> 6, lane = tid & 63;
  const int wm = (wid >> 1) * 64, wn = (wid & 1) * 64;
  const int r16 = lane & 15, quad = lane >> 4;
  const int sw = r16 & 7;

  const int rsub = lane >> 3;
  const int gcol = ((lane & 7) ^ rsub) << 3;

  const unsigned short* Abase = A + (size_t)(m0 + (wid << 5) + rsub) * K + gcol;
  const unsigned short* Bbase = Bt + (size_t)(n0 + (wid << 5) + rsub) * K + gcol;
  unsigned short* lAw = lA + (wid << 5) * 64;
  unsigned short* lBw = lB + (wid << 5) * 64;

  floatx4 acc[4][4] = {};

  for (int k0 = 0; k0 < K; k0 += 64) {
#pragma unroll
    for (int i = 0; i < 4; ++i) {
      gl_lds16(Abase + (size_t)(i * 8) * K + k0, lAw + i * 8 * 64);
      gl_lds16(Bbase + (size_t)(i * 8) * K + k0, lBw + i * 8 * 64);
    }
    __syncthreads();
#pragma unroll
    for (int ks = 0; ks < 2; ++ks) {
      bf16x8 af[4], bfr[4];
#pragma unroll
      for (int i = 0; i < 4; ++i)
        af[i] = *(const bf16x8*)&lA[(wm + i * 16 + r16) * 64 + ((((ks << 2) | quad) ^ sw) << 3)];
#pragma unroll
      for (int j2 = 0; j2 < 4; ++j2)
        bfr[j2] = *(const bf16x8*)&lB[(wn + j2 * 16 + r16) * 64 + ((((ks << 2) | quad) ^ sw) << 3)];
#pragma unroll
      for (int i = 0; i < 4; ++i)
#pragma unroll
        for (int j2 = 0; j2 < 4; ++j2)
          acc[i][j2] = __builtin_amdgcn_mfma_f32_16x16x32_bf16(af[i], bfr[j2], acc[i][j2], 0, 0, 0);
    }
    __syncthreads();
  }

  // ---- epilogue: 4 passes of 32 rows through LDS (fp32, stride 132) ----
  const int row = tid >> 3;   // 0..31
  const int seg = tid & 7;    // 0..7
  const int scol_ = tid & 127;
  const int shalf = tid >> 7;
  float aa = 0.f, sbi = 0.f, ssc = 0.f, a16 = 0.f;
  if (MODE == 0 && n0 < DHID) {
    aa  = a_s[n0 + scol_];
    sbi = bias0[n0 + scol_];
    ssc = a_s[DHID + n0 + scol_];
    float t2 = aa * aa, t4 = t2 * t2, t8 = t4 * t4;
    a16 = t8 * t8;
  }
  const int bb = m0 >> 12;
  const int c0 = (m0 & 4095) >> 5;

#pragma unroll
  for (int p = 0; p < 4; ++p) {
    __syncthreads();
    if ((wid >> 1) == (p >> 1)) {
      const int i0 = (p & 1) * 2;
#pragma unroll
      for (int ii = 0; ii < 2; ++ii) {
        const int i = i0 + ii;
        const int srow = i * 16 + quad * 4 - (p & 1) * 32;
#pragma unroll
        for (int j2 = 0; j2 < 4; ++j2) {
          const int scol = wn + j2 * 16 + r16;
#pragma unroll
          for (int r = 0; r < 4; ++r)
            stg[(srow + r) * 132 + scol] = acc[i][j2][r];
        }
      }
    }
    __syncthreads();

    if (MODE == 0 && n0 < DHID) {
      float P = 0.f;
      const float* sp = &stg[(shalf * 16) * 132 + scol_];
#pragma unroll
      for (int r = 0; r < 16; ++r) {
        P = fmaf(aa, P, (sp[0] + sbi) * ssc);
        sp += 132;
      }
      if (shalf) ltmp[scol_] = P;
      __syncthreads();
      if (!shalf)
        carry[((size_t)bb * NCH2 + c0 + p) * DHID + n0 + scol_] = fmaf(a16, P, ltmp[scol_]);
    }

    const int gm = m0 + p * 32 + row;
    const int col0 = n0 + seg * 16;
    if (MODE == 0) {
      union { unsigned short s[16]; uint4 q[2]; } ub;
      if (n0 < DHID) {
#pragma unroll
        for (int u = 0; u < 4; ++u) {
          float4 v  = *(const float4*)&stg[row * 132 + seg * 16 + u * 4];
          float4 bi = *(const float4*)&bias0[col0 + u * 4];
          float4 sc = *(const float4*)&a_s[DHID + col0 + u * 4];
          ub.s[u * 4 + 0] = f2bf((v.x + bi.x) * sc.x);
          ub.s[u * 4 + 1] = f2bf((v.y + bi.y) * sc.y);
          ub.s[u * 4 + 2] = f2bf((v.z + bi.z) * sc.z);
          ub.s[u * 4 + 3] = f2bf((v.w + bi.w) * sc.w);
        }
        *(uint4*)&u_out[(size_t)gm * DHID + col0]     = ub.q[0];
        *(uint4*)&u_out[(size_t)gm * DHID + col0 + 8] = ub.q[1];
      } else {
        const int c2 = col0 - DHID;
#pragma unroll
        for (int u = 0; u < 4; ++u) {
          float4 v  = *(const float4*)&stg[row * 132 + seg * 16 + u * 4];
          float4 bd = *(const float4*)&bias1[c2 + u * 4];
          ub.s[u * 4 + 0] = f2bf(v.x + bd.x);
          ub.s[u * 4 + 1] = f2bf(v.y + bd.y);
          ub.s[u * 4 + 2] = f2bf(v.z + bd.z);
          ub.s[u * 4 + 3] = f2bf(v.w + bd.w);
        }
        *(uint4*)&dx_buf[(size_t)gm * DOUT + c2]     = ub.q[0];
        *(uint4*)&dx_buf[(size_t)gm * DOUT + c2 + 8] = ub.q[1];
      }
    } else {
#pragma unroll
      for (int u = 0; u < 4; ++u) {
        float4 v  = *(const float4*)&stg[row * 132 + seg * 16 + u * 4];
        float4 bo = *(const float4*)&bias0[col0 + u * 4];
        ushort4 dv = *(const ushort4*)&dx_buf[(size_t)gm * DOUT + col0 + u * 4];
        float4 o;
        o.x = (v.x + bo.x + bf2f(dv.x)) * 0.5f;
        o.y = (v.y + bo.y + bf2f(dv.y)) * 0.5f;
        o.z = (v.z + bo.z + bf2f(dv.z)) * 0.5f;
        o.w = (v.w + bo.w + bf2f(dv.w)) * 0.5f;
        *(float4*)&out[(size_t)gm * DOUT + col0 + u * 4] = o;
      }
    }
  }
}

// ---------- scan kernels ----------
__global__ __launch_bounds__(256) void scan_mid(const float* __restrict__ a_s,
                                                const float* __restrict__ h0,
                                                float* __restrict__ carry,
                                                float* __restrict__ h_last) {
  int idx = blockIdx.x * 256 + threadIdx.x;   // B_*DHID = 8192
  int d = idx & (DHID - 1);
  int b = idx >> 10;
  float a = a_s[d];
  float aL = a;
#pragma unroll
  for (int q = 0; q < 5; ++q) aL *= aL;       // a^32
  float st = h0[(size_t)b * DHID + d];
  float* p = &carry[(size_t)b * NCH2 * DHID + d];
  for (int cg = 0; cg < NCH2; cg += 8) {
    float loc[8];
#pragma unroll
    for (int j = 0; j < 8; ++j) loc[j] = p[(size_t)j * DHID];
#pragma unroll
    for (int j = 0; j < 8; ++j) {
      p[(size_t)j * DHID] = st;
      st = fmaf(aL, st, loc[j]);
    }
    p += (size_t)8 * DHID;
  }
  h_last[(size_t)b * DHID + d] = st;
}

__global__ __launch_bounds__(256) void scan2(unsigned short* __restrict__ u,
                                             const float* __restrict__ a_s,
                                             const float* __restrict__ carry) {
  int idx = blockIdx.x * 256 + threadIdx.x;
  int d8 = (idx & 127) * 8;
  int c  = (idx >> 7) & (NCH2 - 1);
  int b  = idx >> 14;
  float4 a0 = *(const float4*)&a_s[d8];
  float4 a1 = *(const float4*)&a_s[d8 + 4];
  const float* cp = &carry[((size_t)(b * NCH2 + c)) * DHID + d8];
  float4 e0 = *(const float4*)cp;
  float4 e1 = *(const float4*)(cp + 4);
  float h0_ = e0.x, h1 = e0.y, h2 = e0.z, h3 = e0.w;
  float h4 = e1.x, h5 = e1.y, h6 = e1.z, h7 = e1.w;
  unsigned short* up = u + ((size_t)(b * S_ + c * CH2)) * DHID + d8;
#pragma unroll 4
  for (int t = 0; t < CH2; ++t) {
    ushort4 q0 = *(const ushort4*)up;
    ushort4 q1 = *(const ushort4*)(up + 4);
    h0_ = fmaf(a0.x, h0_, bf2f(q0.x)); h1 = fmaf(a0.y, h1, bf2f(q0.y));
    h2  = fmaf(a0.z, h2,  bf2f(q0.z)); h3 = fmaf(a0.w, h3, bf2f(q0.w));
    h4  = fmaf(a1.x, h4,  bf2f(q1.x)); h5 = fmaf(a1.y, h5, bf2f(q1.y));
    h6  = fmaf(a1.z, h6,  bf2f(q1.z)); h7 = fmaf(a1.w, h7, bf2f(q1.w));
    ushort4 w0, w1;
    w0.x = f2bf(h0_); w0.y = f2bf(h1); w0.z = f2bf(h2); w0.w = f2bf(h3);
    w1.x = f2bf(h4);  w1.y = f2bf(h5); w1.z = f2bf(h6); w1.w = f2bf(h7);
    *(ushort4*)up = w0;
    *(ushort4*)(up + 4) = w1;
    up += DHID;
  }
}

extern "C" void kernel_launch(void* const* d_in, const int* in_sizes, int n_in,
                              void* d_out, int out_size, void* d_ws, size_t ws_size,
                              hipStream_t stream) {
  const float* x    = (const float*)d_in[0];
  const float* h0   = (const float*)d_in[1];
  const float* alog = (const float*)d_in[2];
  const float* Wdx  = (const float*)d_in[3];
  const float* bdx  = (const float*)d_in[4];
  const float* Win  = (const float*)d_in[5];
  const float* bin  = (const float*)d_in[6];
  const float* Wout = (const float*)d_in[7];
  const float* bout = (const float*)d_in[8];

  float* out    = (float*)d_out;
  float* h_last = out + (size_t)M_ * DOUT;

  char* ws = (char*)d_ws;
  unsigned short* xb    = (unsigned short*)(ws);                      // 32 MB
  unsigned short* ubuf  = (unsigned short*)(ws + 33554432ull);        // 64 MB (u -> h in-place)
  unsigned short* dxb   = (unsigned short*)(ws + 100663296ull);       // 32 MB
  unsigned short* wcat  = (unsigned short*)(ws + 134217728ull);       // 1.5 MB
  unsigned short* woutt = (unsigned short*)(ws + 135790592ull);       // 1 MB
  float*          a_s   = (float*)(ws + 136839168ull);                // 8 KB
  float*          carry = (float*)(ws + 136847360ull);                // 4 MB

  // 1 launch: all weight transposes + gate precompute + x->bf16
  prep_all<<<5124 + (M_ * DIN / 8) / 256, 256, 0, stream>>>(
      alog, Win, Wdx, Wout, x, a_s, wcat, woutt, xb);

  // GEMM1 (+fused chunk-local scan): 256^2 tile, 4-deep counted-vmcnt pipeline
  gemm1<<<dim3((M_ / 256) * (NCAT / 256)), dim3(512), 0, stream>>>(
      xb, wcat, a_s, bin, bdx, ubuf, dxb, carry);

  // prefix over chunks + h_last
  scan_mid<<<(B_ * DHID) / 256, 256, 0, stream>>>(a_s, h0, carry, h_last);
  // full scan from exact entry states, u -> h in place
  scan2   <<<(B_ * NCH2 * (DHID / 8)) / 256, 256, 0, stream>>>(ubuf, a_s, carry);

  // GEMM2: out = (dx + h@W_out + b_out)/2
  gemm_bt<DHID, 1, 4><<<dim3(DOUT / 128, M_ / 128), 256, 0, stream>>>(
      ubuf, woutt, a_s, bout, nullptr, nullptr, dxb, out, nullptr);
}

// Round 2
// 270.153 us; speedup vs baseline: 1.0486x; 1.0308x over previous
//
#include <hip/hip_runtime.h>

// Problem constants (B,S,D_IN,D_HID,D_OUT) = (8,4096,512,1024,512)
#define B_    8
#define S_    4096
#define DIN   512
#define DHID  1024
#define DOUT  512
#define M_    (B_*S_)          // 32768
#define NCAT  (DHID + DOUT)    // 1536
#define CH2   32
#define NCH2  (S_/CH2)         // 128

typedef __bf16 bf16x8 __attribute__((ext_vector_type(8)));
typedef float  floatx4 __attribute__((ext_vector_type(4)));

__device__ __forceinline__ unsigned short f2bf(float f) {
  unsigned u = __builtin_bit_cast(unsigned, f);
  u = (u + 0x7FFFu + ((u >> 16) & 1u)) >> 16;   // RNE
  return (unsigned short)u;
}
__device__ __forceinline__ float bf2f(unsigned short h) {
  unsigned u = ((unsigned)h) << 16;
  return __builtin_bit_cast(float, u);
}

__device__ __forceinline__ void gl_lds16(const unsigned short* g, unsigned short* l) {
  __builtin_amdgcn_global_load_lds((const __attribute__((address_space(1))) void*)g,
                                   (__attribute__((address_space(3))) void*)l, 16, 0, 0);
}

// ---------- fused prep: wcat | woutt | a_s | x->bf16 (single launch) ----------
__global__ void prep_all(const float* __restrict__ logit,
                         const float* __restrict__ Win, const float* __restrict__ Wdx,
                         const float* __restrict__ Wout, const float* __restrict__ x,
                         float* __restrict__ a_s,
                         unsigned short* __restrict__ wcat,
                         unsigned short* __restrict__ woutt,
                         unsigned short* __restrict__ xb) {
  int bx = blockIdx.x;
  if (bx < 3072) {                       // Wcat^T: n in [0,1536), k in [0,512)
    int idx = bx * 256 + threadIdx.x;
    int n = idx >> 9, k = idx & 511;
    float v = (n < DHID) ? Win[(size_t)k * DHID + n] : Wdx[(size_t)k * DOUT + (n - DHID)];
    wcat[idx] = f2bf(v);
  } else if (bx < 5120) {                // Wout^T: n in [0,512), k in [0,1024)
    int idx = (bx - 3072) * 256 + threadIdx.x;
    int n = idx >> 10, k = idx & 1023;
    woutt[idx] = f2bf(Wout[(size_t)k * DOUT + n]);
  } else if (bx < 5124) {                // a_s
    int d = (bx - 5120) * 256 + threadIdx.x;
    if (d < DHID) {
      float a = 1.f / (1.f + expf(-logit[d]));
      a_s[d] = a;
      a_s[DHID + d] = sqrtf(fmaxf(1.f - a * a, 0.f));
    }
  } else {                               // x fp32 -> bf16, 8 elems/thread
    size_t i = (size_t)(bx - 5124) * 256 + threadIdx.x;
    const float4* p = (const float4*)x;
    float4 v0 = p[i * 2];
    float4 v1 = p[i * 2 + 1];
    uint4 o;
    o.x = (unsigned)f2bf(v0.x) | ((unsigned)f2bf(v0.y) << 16);
    o.y = (unsigned)f2bf(v0.z) | ((unsigned)f2bf(v0.w) << 16);
    o.z = (unsigned)f2bf(v1.x) | ((unsigned)f2bf(v1.y) << 16);
    o.w = (unsigned)f2bf(v1.z) | ((unsigned)f2bf(v1.w) << 16);
    *(uint4*)&xb[i * 8] = o;
  }
}

// ---------- unified 256x256 GEMM, fine-phased pipeline ----------
// Granule = 32-K slab (A 256x32 + B 256x32 bf16, 16KB+16KB), 4 LDS slots, prefetch
// distance 3, vmcnt(8) once per granule (never 0 until tail). Each granule = 2 phases
// (i-halves, 16 MFMA each): {ds_read ; 2x global_load_lds ; s_barrier ; lgkmcnt(0) ;
// setprio(1) MFMA setprio(0) ; s_barrier}. Swizzle (proven r0): LDS linear for
// global_load_lds, source chunk pre-XOR'd, ds_read chunk ^= ((row>>1)&3) -> 2-way free.
// MODE 0: C = xb @ Wcat^T; n0<1024: u=(c+b_in)*s bf16 + fused chunk-scan -> carry;
//         else dx=c+b_dx bf16.   MODE 1: out = (c + b_out + dx)*0.5 fp32.
template <int K, int MODE, int NTN>
__global__ __launch_bounds__(512, 2) void gemm256(
    const unsigned short* __restrict__ A,
    const unsigned short* __restrict__ Bt,
    const float* __restrict__ a_s,
    const float* __restrict__ bias0,
    const float* __restrict__ bias1,
    unsigned short* __restrict__ u_out,
    unsigned short* __restrict__ dx_buf,
    const unsigned short* __restrict__ dx_in,
    float* __restrict__ out,
    float* __restrict__ carry)
{
  constexpr int NG = K / 32;             // granules
  __shared__ __align__(16) unsigned char smem[131072];
  unsigned char* lds = smem;

  const int tid  = threadIdx.x;
  const int lane = tid & 63, wid = tid >> 6;
  const int r16  = lane & 15, quad = lane >> 4;
  const int wm = (wid >> 2) * 128, wn = (wid & 3) * 64;
  const int csw = (quad ^ ((r16 >> 1) & 3)) << 4;   // read-side swizzled 16B chunk

  // XCD-aware bijective block swizzle
  constexpr int TOT = (M_ / 256) * NTN;
  const int flat = blockIdx.x;
  const int jj = (flat & 7) * (TOT / 8) + (flat >> 3);
  const int nt = jj % NTN, mt = jj / NTN;
  const int n0 = nt * 256, m0 = mt * 256;

  // staging addresses (identical involution to read side, proven r0)
  const int srow = (wid << 4) + (lane >> 2);                 // 0..127
  const int scol = ((lane & 3) ^ ((lane >> 3) & 3)) << 3;    // pre-swizzled src chunk
  const unsigned short* gA0 = A  + (size_t)(m0 + srow) * K + scol;
  const unsigned short* gB0 = Bt + (size_t)(n0 + srow) * K + scol;
  const unsigned oA = (unsigned)wid * 1024u + (unsigned)lane * 16u;  // linear LDS bytes

  floatx4 acc[8][4] = {};
  bf16x8 af[4], bf[4];

  auto stageA = [&](int g) {
    unsigned short* d = (unsigned short*)(lds + (g & 3) * 32768 + oA);
    const unsigned short* s = gA0 + (size_t)g * 32;
    gl_lds16(s, d);
    gl_lds16(s + (size_t)128 * K, d + 4096);
  };
  auto stageB = [&](int g) {
    unsigned short* d = (unsigned short*)(lds + (g & 3) * 32768 + 16384 + oA);
    const unsigned short* s = gB0 + (size_t)g * 32;
    gl_lds16(s, d);
    gl_lds16(s + (size_t)128 * K, d + 4096);
  };

  auto phA = [&](int g, int gs, bool st) {
    const unsigned char* sl = lds + (g & 3) * 32768;
#pragma unroll
    for (int j = 0; j < 4; ++j)
      bf[j] = *(const bf16x8*)(sl + 16384 + (wn + j * 16 + r16) * 64 + csw);
#pragma unroll
    for (int i = 0; i < 4; ++i)
      af[i] = *(const bf16x8*)(sl + (wm + i * 16 + r16) * 64 + csw);
    if (st) stageA(gs);
    asm volatile("s_barrier" ::: "memory");
    asm volatile("s_waitcnt lgkmcnt(0)" ::: "memory");
    __builtin_amdgcn_sched_barrier(0);
    __builtin_amdgcn_s_setprio(1);
#pragma unroll
    for (int i = 0; i < 4; ++i)
#pragma unroll
      for (int j = 0; j < 4; ++j)
        acc[i][j] = __builtin_amdgcn_mfma_f32_16x16x32_bf16(af[i], bf[j], acc[i][j], 0, 0, 0);
    __builtin_amdgcn_s_setprio(0);
    asm volatile("s_barrier" ::: "memory");
  };
  auto phB = [&](int g, int gs, bool st) {
    const unsigned char* sl = lds + (g & 3) * 32768;
#pragma unroll
    for (int i = 0; i < 4; ++i)
      af[i] = *(const bf16x8*)(sl + (wm + (4 + i) * 16 + r16) * 64 + csw);
    if (st) stageB(gs);
    asm volatile("s_barrier" ::: "memory");
    asm volatile("s_waitcnt lgkmcnt(0)" ::: "memory");
    __builtin_amdgcn_sched_barrier(0);
    __builtin_amdgcn_s_setprio(1);
#pragma unroll
    for (int i = 0; i < 4; ++i)
#pragma unroll
      for (int j = 0; j < 4; ++j)
        acc[4 + i][j] = __builtin_amdgcn_mfma_f32_16x16x32_bf16(af[i], bf[j], acc[4 + i][j], 0, 0, 0);
    __builtin_amdgcn_s_setprio(0);
    // caller inserts vmcnt + barrier
  };

  // prologue: granules 0,1,2 in flight (12 instrs); wait g0 landed (8 newer allowed)
  stageA(0); stageB(0); stageA(1); stageB(1); stageA(2); stageB(2);
  asm volatile("s_waitcnt vmcnt(8)" ::: "memory");
  asm volatile("s_barrier" ::: "memory");

  // steady state: compute g, stage g+3 (slot of g-1, freed), wait g+1 landed
  for (int g = 0; g < NG - 3; ++g) {
    phA(g, g + 3, true);
    phB(g, g + 3, true);
    asm volatile("s_waitcnt vmcnt(8)" ::: "memory");
    asm volatile("s_barrier" ::: "memory");
  }
  phA(NG - 3, 0, false); phB(NG - 3, 0, false);
  asm volatile("s_waitcnt vmcnt(4)" ::: "memory");
  asm volatile("s_barrier" ::: "memory");
  phA(NG - 2, 0, false); phB(NG - 2, 0, false);
  asm volatile("s_waitcnt vmcnt(0)" ::: "memory");
  asm volatile("s_barrier" ::: "memory");
  phA(NG - 1, 0, false); phB(NG - 1, 0, false);
  asm volatile("s_barrier" ::: "memory");

  // ---- epilogue: 4 passes of 64 rows through LDS (fp32, stride 260) ----
  float* stg = (float*)smem;
  const bool isU = (MODE == 0) && (n0 < DHID);
  const int c4 = lane << 2;              // col base 0..252 (row-contiguous reads)

  float4 bv = {}, sv = {};
  if (MODE == 0) {
    if (isU) { bv = *(const float4*)&bias0[n0 + c4]; sv = *(const float4*)&a_s[DHID + n0 + c4]; }
    else     { bv = *(const float4*)&bias1[(n0 - DHID) + c4]; }
  } else {
    bv = *(const float4*)&bias0[n0 + c4];
  }

  // fused-scan mapping: 512 threads = 256 cols x 2 chunks of 32 rows
  const int colS = tid & 255, ch = tid >> 8;
  float aa = 0.f, sbi = 0.f, ssc = 0.f;
  if (isU) { aa = a_s[n0 + colS]; sbi = bias0[n0 + colS]; ssc = a_s[DHID + n0 + colS]; }

#pragma unroll
  for (int p = 0; p < 4; ++p) {
    if ((wid >> 2) == (p >> 1)) {
      const int ib = (p & 1) * 4;
#pragma unroll
      for (int ii = 0; ii < 4; ++ii)
#pragma unroll
        for (int j = 0; j < 4; ++j) {
          const int col = (wid & 3) * 64 + j * 16 + r16;
#pragma unroll
          for (int r = 0; r < 4; ++r)
            stg[(ii * 16 + quad * 4 + r) * 260 + col] = acc[ib + ii][j][r];
        }
    }
    asm volatile("s_waitcnt lgkmcnt(0)" ::: "memory");
    asm volatile("s_barrier" ::: "memory");

    const int gmb = m0 + p * 64;
    if (isU) {
      // chunk-local weighted scan over 32 rows -> carry
      float P = 0.f;
      const float* sp = &stg[(ch * 32) * 260 + colS];
#pragma unroll
      for (int r = 0; r < 32; ++r) { P = fmaf(aa, P, (sp[0] + sbi) * ssc); sp += 260; }
      const int gm0 = gmb + ch * 32;
      carry[((size_t)(gm0 >> 12) * NCH2 + ((gm0 & 4095) >> 5)) * DHID + n0 + colS] = P;
      // u = (c + b_in) * s  (bf16), 8 rows per wave, row-contiguous LDS reads
#pragma unroll
      for (int rr = 0; rr < 8; ++rr) {
        const int lr = (wid << 3) + rr;
        float4 v = *(const float4*)&stg[lr * 260 + c4];
        ushort4 o;
        o.x = f2bf((v.x + bv.x) * sv.x);
        o.y = f2bf((v.y + bv.y) * sv.y);
        o.z = f2bf((v.z + bv.z) * sv.z);
        o.w = f2bf((v.w + bv.w) * sv.w);
        *(ushort4*)&u_out[(size_t)(gmb + lr) * DHID + n0 + c4] = o;
      }
    } else if (MODE == 0) {
#pragma unroll
      for (int rr = 0; rr < 8; ++rr) {
        const int lr = (wid << 3) + rr;
        float4 v = *(const float4*)&stg[lr * 260 + c4];
        ushort4 o;
        o.x = f2bf(v.x + bv.x);
        o.y = f2bf(v.y + bv.y);
        o.z = f2bf(v.z + bv.z);
        o.w = f2bf(v.w + bv.w);
        *(ushort4*)&dx_buf[(size_t)(gmb + lr) * DOUT + (n0 - DHID) + c4] = o;
      }
    } else {
#pragma unroll
      for (int rr = 0; rr < 8; ++rr) {
        const int lr = (wid << 3) + rr;
        float4 v = *(const float4*)&stg[lr * 260 + c4];
        ushort4 dv = *(const ushort4*)&dx_in[(size_t)(gmb + lr) * DOUT + n0 + c4];
        float4 o;
        o.x = (v.x + bv.x + bf2f(dv.x)) * 0.5f;
        o.y = (v.y + bv.y + bf2f(dv.y)) * 0.5f;
        o.z = (v.z + bv.z + bf2f(dv.z)) * 0.5f;
        o.w = (v.w + bv.w + bf2f(dv.w)) * 0.5f;
        *(float4*)&out[(size_t)(gmb + lr) * DOUT + n0 + c4] = o;
      }
    }
    asm volatile("s_barrier" ::: "memory");
  }
}

// ---------- scan kernels ----------
__global__ __launch_bounds__(256) void scan_mid(const float* __restrict__ a_s,
                                                const float* __restrict__ h0,
                                                float* __restrict__ carry,
                                                float* __restrict__ h_last) {
  int idx = blockIdx.x * 256 + threadIdx.x;   // B_*DHID = 8192
  int d = idx & (DHID - 1);
  int b = idx >> 10;
  float a = a_s[d];
  float aL = a;
#pragma unroll
  for (int q = 0; q < 5; ++q) aL *= aL;       // a^32
  float st = h0[(size_t)b * DHID + d];
  float* p = &carry[(size_t)b * NCH2 * DHID + d];
  for (int cg = 0; cg < NCH2; cg += 8) {
    float loc[8];
#pragma unroll
    for (int j = 0; j < 8; ++j) loc[j] = p[(size_t)j * DHID];
#pragma unroll
    for (int j = 0; j < 8; ++j) {
      p[(size_t)j * DHID] = st;
      st = fmaf(aL, st, loc[j]);
    }
    p += (size_t)8 * DHID;
  }
  h_last[(size_t)b * DHID + d] = st;
}

__global__ __launch_bounds__(256) void scan2(unsigned short* __restrict__ u,
                                             const float* __restrict__ a_s,
                                             const float* __restrict__ carry) {
  int idx = blockIdx.x * 256 + threadIdx.x;
  int d8 = (idx & 127) * 8;
  int c  = (idx >> 7) & (NCH2 - 1);
  int b  = idx >> 14;
  float4 a0 = *(const float4*)&a_s[d8];
  float4 a1 = *(const float4*)&a_s[d8 + 4];
  const float* cp = &carry[((size_t)(b * NCH2 + c)) * DHID + d8];
  float4 e0 = *(const float4*)cp;
  float4 e1 = *(const float4*)(cp + 4);
  float h0_ = e0.x, h1 = e0.y, h2 = e0.z, h3 = e0.w;
  float h4 = e1.x, h5 = e1.y, h6 = e1.z, h7 = e1.w;
  unsigned short* up = u + ((size_t)(b * S_ + c * CH2)) * DHID + d8;
#pragma unroll 4
  for (int t = 0; t < CH2; ++t) {
    ushort4 q0 = *(const ushort4*)up;
    ushort4 q1 = *(const ushort4*)(up + 4);
    h0_ = fmaf(a0.x, h0_, bf2f(q0.x)); h1 = fmaf(a0.y, h1, bf2f(q0.y));
    h2  = fmaf(a0.z, h2,  bf2f(q0.z)); h3 = fmaf(a0.w, h3, bf2f(q0.w));
    h4  = fmaf(a1.x, h4,  bf2f(q1.x)); h5 = fmaf(a1.y, h5, bf2f(q1.y));
    h6  = fmaf(a1.z, h6,  bf2f(q1.z)); h7 = fmaf(a1.w, h7, bf2f(q1.w));
    ushort4 w0, w1;
    w0.x = f2bf(h0_); w0.y = f2bf(h1); w0.z = f2bf(h2); w0.w = f2bf(h3);
    w1.x = f2bf(h4);  w1.y = f2bf(h5); w1.z = f2bf(h6); w1.w = f2bf(h7);
    *(ushort4*)up = w0;
    *(ushort4*)(up + 4) = w1;
    up += DHID;
  }
}

extern "C" void kernel_launch(void* const* d_in, const int* in_sizes, int n_in,
                              void* d_out, int out_size, void* d_ws, size_t ws_size,
                              hipStream_t stream) {
  const float* x    = (const float*)d_in[0];
  const float* h0   = (const float*)d_in[1];
  const float* alog = (const float*)d_in[2];
  const float* Wdx  = (const float*)d_in[3];
  const float* bdx  = (const float*)d_in[4];
  const float* Win  = (const float*)d_in[5];
  const float* bin  = (const float*)d_in[6];
  const float* Wout = (const float*)d_in[7];
  const float* bout = (const float*)d_in[8];

  float* out    = (float*)d_out;
  float* h_last = out + (size_t)M_ * DOUT;

  char* ws = (char*)d_ws;
  unsigned short* xb    = (unsigned short*)(ws);                      // 32 MB
  unsigned short* ubuf  = (unsigned short*)(ws + 33554432ull);        // 64 MB (u -> h in-place)
  unsigned short* dxb   = (unsigned short*)(ws + 100663296ull);       // 32 MB
  unsigned short* wcat  = (unsigned short*)(ws + 134217728ull);       // 1.5 MB
  unsigned short* woutt = (unsigned short*)(ws + 135790592ull);       // 1 MB
  float*          a_s   = (float*)(ws + 136839168ull);                // 8 KB
  float*          carry = (float*)(ws + 136847360ull);                // 4 MB

  // 1 launch: all weight transposes + gate precompute + x->bf16
  prep_all<<<5124 + (M_ * DIN / 8) / 256, 256, 0, stream>>>(
      alog, Win, Wdx, Wout, x, a_s, wcat, woutt, xb);

  // GEMM1 (+fused chunk-local scan): 256^2 tile, fine-phased pipeline
  gemm256<DIN, 0, 6><<<dim3((M_ / 256) * 6), dim3(512), 0, stream>>>(
      xb, wcat, a_s, bin, bdx, ubuf, dxb, nullptr, nullptr, carry);

  // prefix over chunks + h_last
  scan_mid<<<(B_ * DHID) / 256, 256, 0, stream>>>(a_s, h0, carry, h_last);
  // full scan from exact entry states, u -> h in place
  scan2   <<<(B_ * NCH2 * (DHID / 8)) / 256, 256, 0, stream>>>(ubuf, a_s, carry);

  // GEMM2: out = (dx + h@W_out + b_out)/2
  gemm256<DHID, 1, 2><<<dim3((M_ / 256) * 2), dim3(512), 0, stream>>>(
      ubuf, woutt, a_s, bout, nullptr, nullptr, nullptr, dxb, out, nullptr);
}

// Round 3
// 266.863 us; speedup vs baseline: 1.0616x; 1.0123x over previous
//
#include <hip/hip_runtime.h>

// Problem constants (B,S,D_IN,D_HID,D_OUT) = (8,4096,512,1024,512)
#define B_    8
#define S_    4096
#define DIN   512
#define DHID  1024
#define DOUT  512
#define M_    (B_*S_)          // 32768
#define NCAT  (DHID + DOUT)    // 1536
#define CH2   32
#define NCH2  (S_/CH2)         // 128

typedef __bf16 bf16x8 __attribute__((ext_vector_type(8)));
typedef float  floatx4 __attribute__((ext_vector_type(4)));

__device__ __forceinline__ unsigned short f2bf(float f) {
  unsigned u = __builtin_bit_cast(unsigned, f);
  u = (u + 0x7FFFu + ((u >> 16) & 1u)) >> 16;   // RNE
  return (unsigned short)u;
}
__device__ __forceinline__ float bf2f(unsigned short h) {
  unsigned u = ((unsigned)h) << 16;
  return __builtin_bit_cast(float, u);
}

__device__ __forceinline__ void gl_lds16(const unsigned short* g, unsigned short* l) {
  __builtin_amdgcn_global_load_lds((const __attribute__((address_space(1))) void*)g,
                                   (__attribute__((address_space(3))) void*)l, 16, 0, 0);
}

// ---------- fused prep: wcat | woutt | a_s | x->bf16 (single launch) ----------
__global__ void prep_all(const float* __restrict__ logit,
                         const float* __restrict__ Win, const float* __restrict__ Wdx,
                         const float* __restrict__ Wout, const float* __restrict__ x,
                         float* __restrict__ a_s,
                         unsigned short* __restrict__ wcat,
                         unsigned short* __restrict__ woutt,
                         unsigned short* __restrict__ xb) {
  int bx = blockIdx.x;
  if (bx < 3072) {                       // Wcat^T: n in [0,1536), k in [0,512)
    int idx = bx * 256 + threadIdx.x;
    int n = idx >> 9, k = idx & 511;
    float v = (n < DHID) ? Win[(size_t)k * DHID + n] : Wdx[(size_t)k * DOUT + (n - DHID)];
    wcat[idx] = f2bf(v);
  } else if (bx < 5120) {                // Wout^T: n in [0,512), k in [0,1024)
    int idx = (bx - 3072) * 256 + threadIdx.x;
    int n = idx >> 10, k = idx & 1023;
    woutt[idx] = f2bf(Wout[(size_t)k * DOUT + n]);
  } else if (bx < 5124) {                // a_s
    int d = (bx - 5120) * 256 + threadIdx.x;
    if (d < DHID) {
      float a = 1.f / (1.f + expf(-logit[d]));
      a_s[d] = a;
      a_s[DHID + d] = sqrtf(fmaxf(1.f - a * a, 0.f));
    }
  } else {                               // x fp32 -> bf16, 8 elems/thread
    size_t i = (size_t)(bx - 5124) * 256 + threadIdx.x;
    const float4* p = (const float4*)x;
    float4 v0 = p[i * 2];
    float4 v1 = p[i * 2 + 1];
    uint4 o;
    o.x = (unsigned)f2bf(v0.x) | ((unsigned)f2bf(v0.y) << 16);
    o.y = (unsigned)f2bf(v0.z) | ((unsigned)f2bf(v0.w) << 16);
    o.z = (unsigned)f2bf(v1.x) | ((unsigned)f2bf(v1.y) << 16);
    o.w = (unsigned)f2bf(v1.z) | ((unsigned)f2bf(v1.w) << 16);
    *(uint4*)&xb[i * 8] = o;
  }
}

// ---------- unified 256x256 GEMM, coarse counted-vmcnt pipeline (r1-proven) ----------
// Granule = 32-K slab (A 256x32 + B 256x32 bf16), 4 LDS slots, prefetch distance 3,
// per granule: stage(t+3) -> 12 ds_read_b128 -> 32 MFMA -> vmcnt(8)+lgkmcnt(0) -> barrier.
// Swizzle: LDS linear for global_load_lds, source chunk pre-XOR'd, ds_read chunk
// ^= ((row>>1)&3) -> 2-way (free) bank access. Epilogue: r2-proven conflict-free.
// MODE 0: C = xb @ Wcat^T; n0<1024: u=(c+b_in)*s bf16 + fused chunk-scan -> carry;
//         else dx=c+b_dx bf16.   MODE 1: out = (c + b_out + dx)*0.5 fp32.
template <int K, int MODE, int NTN>
__global__ __launch_bounds__(512, 2) void gemm256(
    const unsigned short* __restrict__ A,
    const unsigned short* __restrict__ Bt,
    const float* __restrict__ a_s,
    const float* __restrict__ bias0,
    const float* __restrict__ bias1,
    unsigned short* __restrict__ u_out,
    unsigned short* __restrict__ dx_buf,
    const unsigned short* __restrict__ dx_in,
    float* __restrict__ out,
    float* __restrict__ carry)
{
  constexpr int NG = K / 32;             // granules
  __shared__ __align__(16) unsigned char smem[131072];
  unsigned char* lds = smem;

  const int tid  = threadIdx.x;
  const int lane = tid & 63, wid = tid >> 6;
  const int r16  = lane & 15, quad = lane >> 4;
  const int wm = (wid >> 2) * 128, wn = (wid & 3) * 64;
  const int csw = (quad ^ ((r16 >> 1) & 3)) << 4;   // read-side swizzled 16B chunk

  // XCD-aware bijective block swizzle
  constexpr int TOT = (M_ / 256) * NTN;
  const int flat = blockIdx.x;
  const int jj = (flat & 7) * (TOT / 8) + (flat >> 3);
  const int nt = jj % NTN, mt = jj / NTN;
  const int n0 = nt * 256, m0 = mt * 256;

  // staging addresses (source pre-swizzled with the same involution as the read side)
  const int srow = (wid << 4) + (lane >> 2);                 // 0..127
  const int scol = ((lane & 3) ^ ((lane >> 3) & 3)) << 3;    // pre-swizzled src chunk
  const unsigned short* gA0 = A  + (size_t)(m0 + srow) * K + scol;
  const unsigned short* gB0 = Bt + (size_t)(n0 + srow) * K + scol;
  const unsigned oA = (unsigned)wid * 1024u + (unsigned)lane * 16u;  // linear LDS bytes

  floatx4 acc[8][4] = {};

  auto stage = [&](int slot, int g) {
    unsigned char* d = lds + slot * 32768;
    const unsigned short* sa = gA0 + (size_t)g * 32;
    const unsigned short* sb = gB0 + (size_t)g * 32;
    gl_lds16(sa, (unsigned short*)(d + oA));
    gl_lds16(sa + (size_t)128 * K, (unsigned short*)(d + oA + 8192));
    gl_lds16(sb, (unsigned short*)(d + 16384 + oA));
    gl_lds16(sb + (size_t)128 * K, (unsigned short*)(d + 16384 + oA + 8192));
  };

  auto compute = [&](int slot) {
    const unsigned char* pA = lds + slot * 32768;
    const unsigned char* pB = pA + 16384;
    bf16x8 af[8], bfr[4];
#pragma unroll
    for (int j = 0; j < 4; ++j)
      bfr[j] = *(const bf16x8*)(pB + (wn + j * 16 + r16) * 64 + csw);
#pragma unroll
    for (int i = 0; i < 8; ++i)
      af[i] = *(const bf16x8*)(pA + (wm + i * 16 + r16) * 64 + csw);
    __builtin_amdgcn_s_setprio(1);
#pragma unroll
    for (int i = 0; i < 8; ++i)
#pragma unroll
      for (int j = 0; j < 4; ++j)
        acc[i][j] = __builtin_amdgcn_mfma_f32_16x16x32_bf16(af[i], bfr[j], acc[i][j], 0, 0, 0);
    __builtin_amdgcn_s_setprio(0);
  };

  // prologue: granules 0,1,2 in flight (12 loads); wait g0 landed (8 newer allowed)
  stage(0, 0); stage(1, 1); stage(2, 2);
  asm volatile("s_waitcnt vmcnt(8)" ::: "memory");
  __builtin_amdgcn_s_barrier();

  // steady state: stage g+3 (slot of g-1, freed), compute g, wait g+1 landed
  for (int t = 0; t < NG - 3; ++t) {
    stage((t + 3) & 3, t + 3);
    compute(t & 3);
    asm volatile("s_waitcnt vmcnt(8) lgkmcnt(0)" ::: "memory");
    __builtin_amdgcn_s_barrier();
  }
  compute((NG - 3) & 3);
  asm volatile("s_waitcnt vmcnt(4) lgkmcnt(0)" ::: "memory");
  __builtin_amdgcn_s_barrier();
  compute((NG - 2) & 3);
  asm volatile("s_waitcnt vmcnt(0) lgkmcnt(0)" ::: "memory");
  __builtin_amdgcn_s_barrier();
  compute((NG - 1) & 3);
  asm volatile("s_waitcnt lgkmcnt(0)" ::: "memory");
  __builtin_amdgcn_s_barrier();

  // ---- epilogue (r2-proven, conflict-free): 4 passes of 64 rows, fp32 stride 260 ----
  float* stg = (float*)smem;
  const bool isU = (MODE == 0) && (n0 < DHID);
  const int c4 = lane << 2;              // col base 0..252 (row-contiguous reads)

  float4 bv = {}, sv = {};
  if (MODE == 0) {
    if (isU) { bv = *(const float4*)&bias0[n0 + c4]; sv = *(const float4*)&a_s[DHID + n0 + c4]; }
    else     { bv = *(const float4*)&bias1[(n0 - DHID) + c4]; }
  } else {
    bv = *(const float4*)&bias0[n0 + c4];
  }

  // fused-scan mapping: 512 threads = 256 cols x 2 chunks of 32 rows
  const int colS = tid & 255, ch = tid >> 8;
  float aa = 0.f, sbi = 0.f, ssc = 0.f;
  if (isU) { aa = a_s[n0 + colS]; sbi = bias0[n0 + colS]; ssc = a_s[DHID + n0 + colS]; }

#pragma unroll
  for (int p = 0; p < 4; ++p) {
    if ((wid >> 2) == (p >> 1)) {
      const int ib = (p & 1) * 4;
#pragma unroll
      for (int ii = 0; ii < 4; ++ii)
#pragma unroll
        for (int j = 0; j < 4; ++j) {
          const int col = (wid & 3) * 64 + j * 16 + r16;
#pragma unroll
          for (int r = 0; r < 4; ++r)
            stg[(ii * 16 + quad * 4 + r) * 260 + col] = acc[ib + ii][j][r];
        }
    }
    asm volatile("s_waitcnt lgkmcnt(0)" ::: "memory");
    __builtin_amdgcn_s_barrier();

    const int gmb = m0 + p * 64;
    if (isU) {
      // chunk-local weighted scan over 32 rows -> carry
      float P = 0.f;
      const float* sp = &stg[(ch * 32) * 260 + colS];
#pragma unroll
      for (int r = 0; r < 32; ++r) { P = fmaf(aa, P, (sp[0] + sbi) * ssc); sp += 260; }
      const int gm0 = gmb + ch * 32;
      carry[((size_t)(gm0 >> 12) * NCH2 + ((gm0 & 4095) >> 5)) * DHID + n0 + colS] = P;
      // u = (c + b_in) * s  (bf16), 8 rows per wave, row-contiguous LDS reads
#pragma unroll
      for (int rr = 0; rr < 8; ++rr) {
        const int lr = (wid << 3) + rr;
        float4 v = *(const float4*)&stg[lr * 260 + c4];
        ushort4 o;
        o.x = f2bf((v.x + bv.x) * sv.x);
        o.y = f2bf((v.y + bv.y) * sv.y);
        o.z = f2bf((v.z + bv.z) * sv.z);
        o.w = f2bf((v.w + bv.w) * sv.w);
        *(ushort4*)&u_out[(size_t)(gmb + lr) * DHID + n0 + c4] = o;
      }
    } else if (MODE == 0) {
#pragma unroll
      for (int rr = 0; rr < 8; ++rr) {
        const int lr = (wid << 3) + rr;
        float4 v = *(const float4*)&stg[lr * 260 + c4];
        ushort4 o;
        o.x = f2bf(v.x + bv.x);
        o.y = f2bf(v.y + bv.y);
        o.z = f2bf(v.z + bv.z);
        o.w = f2bf(v.w + bv.w);
        *(ushort4*)&dx_buf[(size_t)(gmb + lr) * DOUT + (n0 - DHID) + c4] = o;
      }
    } else {
#pragma unroll
      for (int rr = 0; rr < 8; ++rr) {
        const int lr = (wid << 3) + rr;
        float4 v = *(const float4*)&stg[lr * 260 + c4];
        ushort4 dv = *(const ushort4*)&dx_in[(size_t)(gmb + lr) * DOUT + n0 + c4];
        float4 o;
        o.x = (v.x + bv.x + bf2f(dv.x)) * 0.5f;
        o.y = (v.y + bv.y + bf2f(dv.y)) * 0.5f;
        o.z = (v.z + bv.z + bf2f(dv.z)) * 0.5f;
        o.w = (v.w + bv.w + bf2f(dv.w)) * 0.5f;
        *(float4*)&out[(size_t)(gmb + lr) * DOUT + n0 + c4] = o;
      }
    }
    __builtin_amdgcn_s_barrier();
  }
}

// ---------- scan kernels ----------
__global__ __launch_bounds__(256) void scan_mid(const float* __restrict__ a_s,
                                                const float* __restrict__ h0,
                                                float* __restrict__ carry,
                                                float* __restrict__ h_last) {
  int idx = blockIdx.x * 256 + threadIdx.x;   // B_*DHID = 8192
  int d = idx & (DHID - 1);
  int b = idx >> 10;
  float a = a_s[d];
  float aL = a;
#pragma unroll
  for (int q = 0; q < 5; ++q) aL *= aL;       // a^32
  float st = h0[(size_t)b * DHID + d];
  float* p = &carry[(size_t)b * NCH2 * DHID + d];
  for (int cg = 0; cg < NCH2; cg += 8) {
    float loc[8];
#pragma unroll
    for (int j = 0; j < 8; ++j) loc[j] = p[(size_t)j * DHID];
#pragma unroll
    for (int j = 0; j < 8; ++j) {
      p[(size_t)j * DHID] = st;
      st = fmaf(aL, st, loc[j]);
    }
    p += (size_t)8 * DHID;
  }
  h_last[(size_t)b * DHID + d] = st;
}

__global__ __launch_bounds__(256) void scan2(unsigned short* __restrict__ u,
                                             const float* __restrict__ a_s,
                                             const float* __restrict__ carry) {
  int idx = blockIdx.x * 256 + threadIdx.x;
  int d8 = (idx & 127) * 8;
  int c  = (idx >> 7) & (NCH2 - 1);
  int b  = idx >> 14;
  float4 a0 = *(const float4*)&a_s[d8];
  float4 a1 = *(const float4*)&a_s[d8 + 4];
  const float* cp = &carry[((size_t)(b * NCH2 + c)) * DHID + d8];
  float4 e0 = *(const float4*)cp;
  float4 e1 = *(const float4*)(cp + 4);
  float h0_ = e0.x, h1 = e0.y, h2 = e0.z, h3 = e0.w;
  float h4 = e1.x, h5 = e1.y, h6 = e1.z, h7 = e1.w;
  unsigned short* up = u + ((size_t)(b * S_ + c * CH2)) * DHID + d8;
#pragma unroll 4
  for (int t = 0; t < CH2; ++t) {
    ushort4 q0 = *(const ushort4*)up;
    ushort4 q1 = *(const ushort4*)(up + 4);
    h0_ = fmaf(a0.x, h0_, bf2f(q0.x)); h1 = fmaf(a0.y, h1, bf2f(q0.y));
    h2  = fmaf(a0.z, h2,  bf2f(q0.z)); h3 = fmaf(a0.w, h3, bf2f(q0.w));
    h4  = fmaf(a1.x, h4,  bf2f(q1.x)); h5 = fmaf(a1.y, h5, bf2f(q1.y));
    h6  = fmaf(a1.z, h6,  bf2f(q1.z)); h7 = fmaf(a1.w, h7, bf2f(q1.w));
    ushort4 w0, w1;
    w0.x = f2bf(h0_); w0.y = f2bf(h1); w0.z = f2bf(h2); w0.w = f2bf(h3);
    w1.x = f2bf(h4);  w1.y = f2bf(h5); w1.z = f2bf(h6); w1.w = f2bf(h7);
    *(ushort4*)up = w0;
    *(ushort4*)(up + 4) = w1;
    up += DHID;
  }
}

extern "C" void kernel_launch(void* const* d_in, const int* in_sizes, int n_in,
                              void* d_out, int out_size, void* d_ws, size_t ws_size,
                              hipStream_t stream) {
  const float* x    = (const float*)d_in[0];
  const float* h0   = (const float*)d_in[1];
  const float* alog = (const float*)d_in[2];
  const float* Wdx  = (const float*)d_in[3];
  const float* bdx  = (const float*)d_in[4];
  const float* Win  = (const float*)d_in[5];
  const float* bin  = (const float*)d_in[6];
  const float* Wout = (const float*)d_in[7];
  const float* bout = (const float*)d_in[8];

  float* out    = (float*)d_out;
  float* h_last = out + (size_t)M_ * DOUT;

  char* ws = (char*)d_ws;
  unsigned short* xb    = (unsigned short*)(ws);                      // 32 MB
  unsigned short* ubuf  = (unsigned short*)(ws + 33554432ull);        // 64 MB (u -> h in-place)
  unsigned short* dxb   = (unsigned short*)(ws + 100663296ull);       // 32 MB
  unsigned short* wcat  = (unsigned short*)(ws + 134217728ull);       // 1.5 MB
  unsigned short* woutt = (unsigned short*)(ws + 135790592ull);       // 1 MB
  float*          a_s   = (float*)(ws + 136839168ull);                // 8 KB
  float*          carry = (float*)(ws + 136847360ull);                // 4 MB

  // 1 launch: all weight transposes + gate precompute + x->bf16
  prep_all<<<5124 + (M_ * DIN / 8) / 256, 256, 0, stream>>>(
      alog, Win, Wdx, Wout, x, a_s, wcat, woutt, xb);

  // GEMM1 (+fused chunk-local scan): 256^2 tile, coarse counted-vmcnt pipeline
  gemm256<DIN, 0, 6><<<dim3((M_ / 256) * 6), dim3(512), 0, stream>>>(
      xb, wcat, a_s, bin, bdx, ubuf, dxb, nullptr, nullptr, carry);

  // prefix over chunks + h_last
  scan_mid<<<(B_ * DHID) / 256, 256, 0, stream>>>(a_s, h0, carry, h_last);
  // full scan from exact entry states, u -> h in place
  scan2   <<<(B_ * NCH2 * (DHID / 8)) / 256, 256, 0, stream>>>(ubuf, a_s, carry);

  // GEMM2: out = (dx + h@W_out + b_out)/2
  gemm256<DHID, 1, 2><<<dim3((M_ / 256) * 2), dim3(512), 0, stream>>>(
      ubuf, woutt, a_s, bout, nullptr, nullptr, nullptr, dxb, out, nullptr);
}